// Round 1
// baseline (194.584 us; speedup 1.0000x reference)
//
#include <hip/hip_runtime.h>
#include <hip/hip_bf16.h>
#include <stdint.h>

#define IC 32
#define OC 32
#define HID 32

typedef __attribute__((ext_vector_type(8))) short short8;
typedef __attribute__((ext_vector_type(4))) float f32x4;

static __device__ __forceinline__ short f2bf(float f) {
    __bf16 b = (__bf16)f;
    return __builtin_bit_cast(short, b);
}

// ---------------------------------------------------------------------------
// Zero-init output (harness poisons d_out with 0xAA before every launch)
// ---------------------------------------------------------------------------
__global__ void zero_kernel(float* __restrict__ out, int n) {
    int i = (blockIdx.x * blockDim.x + threadIdx.x) * 4;
    if (i + 3 < n) {
        *(float4*)(out + i) = make_float4(0.f, 0.f, 0.f, 0.f);
    } else {
        for (int k = i; k < n; ++k) out[k] = 0.f;
    }
}

// ---------------------------------------------------------------------------
// Edge branch:
//   h[e,k]   = relu(t_e * eW1[k] + eb1[k])                 (t_e scalar)
//   msg[e,o] = sum_i x[col_e,i] * (sum_k h[e,k]*eW2[k,i*32+o] + eb2[i*32+o])
// As GEMM: Z(E x 1056) @ W2r(1056 x 32), kk = k*32 + i, last 32 kk = bias
// (h==1). Z[e,kk] = h[e,k] * x[col_e,i] is formed in registers:
// per K-step s (=k), lane's A-frag = h[e,s] * xfrag (xfrag fixed per tile).
// Wave: M=16 edges, N=16 outputs (wave parity picks output half).
// B fragments (33 x short8 = 132 VGPRs) register-resident, loaded once.
// mfma_f32_16x16x32_bf16: A[m=lane&15][k=quad*8+j], B[k=quad*8+j][n=lane&15],
// C/D[row=quad*4+reg][col=lane&15].
// ---------------------------------------------------------------------------
__global__ __launch_bounds__(256) void edge_kernel(
    const float* __restrict__ x, const int* __restrict__ edge_index,
    const float* __restrict__ edge_attr,
    const float* __restrict__ eW1, const float* __restrict__ eb1,
    const float* __restrict__ eW2, const float* __restrict__ eb2,
    float* __restrict__ out, int E)
{
    const int tid   = threadIdx.x;
    const int lane  = tid & 63;
    const int gwave = blockIdx.x * 4 + (tid >> 6);
    const int ot    = gwave & 1;            // which 16-wide output tile
    const int tile0 = gwave >> 1;
    const int tstride = (gridDim.x * 4) >> 1;
    const int q     = lane >> 4;
    const int l15   = lane & 15;
    const int ocol  = ot * 16 + l15;

    // --- load B fragments once (register-resident across all edge tiles) ---
    short8 Bf[33];
#pragma unroll
    for (int s = 0; s < 32; ++s) {
        short8 b;
#pragma unroll
        for (int j = 0; j < 8; ++j)
            b[j] = f2bf(eW2[s * 1024 + (q * 8 + j) * 32 + ocol]);
        Bf[s] = b;
    }
    {
        short8 b;
#pragma unroll
        for (int j = 0; j < 8; ++j)
            b[j] = f2bf(eb2[(q * 8 + j) * 32 + ocol]);
        Bf[32] = b;
    }

    const int numTiles = (E + 15) >> 4;
    for (int tile = tile0; tile < numTiles; tile += tstride) {
        const int e16 = tile << 4;
        const int eA  = e16 + l15;
        const bool va = (eA < E);
        const int eAc = va ? eA : 0;
        const float t = va ? edge_attr[eAc] : 0.f;
        const int col = va ? edge_index[E + eAc] : 0;

        // x fragment: x[col, q*8 .. q*8+7] (fixed across all 33 K-steps)
        const float* xp = x + col * IC + q * 8;
        const float4 xlo = *(const float4*)(xp);
        const float4 xhi = *(const float4*)(xp + 4);
        float xf[8] = {xlo.x, xlo.y, xlo.z, xlo.w, xhi.x, xhi.y, xhi.z, xhi.w};

        f32x4 acc = {0.f, 0.f, 0.f, 0.f};
#pragma unroll
        for (int s = 0; s < 32; ++s) {
            float hs = t * eW1[s] + eb1[s];
            hs = hs > 0.f ? hs : 0.f;
            short8 a;
#pragma unroll
            for (int j = 0; j < 8; ++j) a[j] = f2bf(xf[j] * hs);
            acc = __builtin_amdgcn_mfma_f32_16x16x32_bf16(a, Bf[s], acc, 0, 0, 0);
        }
        {   // bias K-step (h == 1): adds sum_i x_i * eb2[i*32+o]
            short8 a;
#pragma unroll
            for (int j = 0; j < 8; ++j) a[j] = f2bf(xf[j]);
            acc = __builtin_amdgcn_mfma_f32_16x16x32_bf16(a, Bf[32], acc, 0, 0, 0);
        }

        // scatter: C row r holds edge e16 + q*4 + r, col = ocol
        const int ebase = e16 + q * 4;
#pragma unroll
        for (int r = 0; r < 4; ++r) {
            const int er = ebase + r;
            if (er < E) {
                const int dst = edge_index[er];   // row (destination node)
                unsafeAtomicAdd(out + dst * OC + ocol, acc[r]);
            }
        }
    }
}

// ---------------------------------------------------------------------------
// Angle branch: feat[a,o] = relu(t_a*aW1 + ab1) @ aW2 + ab2, scatter to j.
// Same MFMA pattern, K=32 (single step), bias added scalar at the end.
// ---------------------------------------------------------------------------
__global__ __launch_bounds__(256) void angle_kernel(
    const float* __restrict__ angles, const int* __restrict__ angle_index,
    const float* __restrict__ aW1, const float* __restrict__ ab1,
    const float* __restrict__ aW2, const float* __restrict__ ab2,
    float* __restrict__ out, int A)
{
    const int tid   = threadIdx.x;
    const int lane  = tid & 63;
    const int gwave = blockIdx.x * 4 + (tid >> 6);
    const int ot    = gwave & 1;
    const int tile0 = gwave >> 1;
    const int tstride = (gridDim.x * 4) >> 1;
    const int q     = lane >> 4;
    const int l15   = lane & 15;
    const int ocol  = ot * 16 + l15;

    short8 Bf;
#pragma unroll
    for (int j = 0; j < 8; ++j)
        Bf[j] = f2bf(aW2[(q * 8 + j) * 32 + ocol]);
    const float bias = ab2[ocol];

    float w1[8], b1[8];
#pragma unroll
    for (int j = 0; j < 8; ++j) {
        w1[j] = aW1[q * 8 + j];
        b1[j] = ab1[q * 8 + j];
    }

    const int numTiles = (A + 15) >> 4;
    for (int tile = tile0; tile < numTiles; tile += tstride) {
        const int a16 = tile << 4;
        const int ai  = a16 + l15;
        const float t = (ai < A) ? angles[ai] : 0.f;

        short8 a;
#pragma unroll
        for (int j = 0; j < 8; ++j) {
            float h = t * w1[j] + b1[j];
            h = h > 0.f ? h : 0.f;
            a[j] = f2bf(h);
        }
        f32x4 acc = {0.f, 0.f, 0.f, 0.f};
        acc = __builtin_amdgcn_mfma_f32_16x16x32_bf16(a, Bf, acc, 0, 0, 0);

        const int abase = a16 + q * 4;
#pragma unroll
        for (int r = 0; r < 4; ++r) {
            const int ar = abase + r;
            if (ar < A) {
                const int dst = angle_index[A + ar];  // center node j
                unsafeAtomicAdd(out + dst * OC + ocol, acc[r] + bias);
            }
        }
    }
}

// ---------------------------------------------------------------------------
extern "C" void kernel_launch(void* const* d_in, const int* in_sizes, int n_in,
                              void* d_out, int out_size, void* d_ws, size_t ws_size,
                              hipStream_t stream)
{
    const float* x          = (const float*)d_in[0];
    const int*   edge_index = (const int*)d_in[1];
    const float* edge_attr  = (const float*)d_in[2];
    const int*   angle_index= (const int*)d_in[3];
    const float* angles     = (const float*)d_in[4];
    const float* eW1        = (const float*)d_in[5];
    const float* eb1        = (const float*)d_in[6];
    const float* eW2        = (const float*)d_in[7];
    const float* eb2        = (const float*)d_in[8];
    const float* aW1        = (const float*)d_in[9];
    const float* ab1        = (const float*)d_in[10];
    const float* aW2        = (const float*)d_in[11];
    const float* ab2        = (const float*)d_in[12];
    float* out = (float*)d_out;

    const int E = in_sizes[1] / 2;
    const int A = in_sizes[3] / 3;

    const int zblocks = (out_size / 4 + 255) / 256;
    zero_kernel<<<zblocks, 256, 0, stream>>>(out, out_size);

    edge_kernel<<<512, 256, 0, stream>>>(x, edge_index, edge_attr,
                                         eW1, eb1, eW2, eb2, out, E);

    angle_kernel<<<512, 256, 0, stream>>>(angles, angle_index,
                                          aW1, ab1, aW2, ab2, out, A);
}